// Round 1
// baseline (1332.669 us; speedup 1.0000x reference)
//
#include <hip/hip_runtime.h>
#include <math.h>

// Problem constants (fixed by the reference)
#define NROWS 200000
#define DDIM  512
#define HDIM  256
#define KHEADS 64
#define BATCH 16              // rows staged in LDS per iteration
#define NBATCH (NROWS / BATCH) // 12500 exactly

// ws layout (floats):
//   [0      : 32768)  qWk_s [64][512]  (pre-scaled by 1/sqrt(H))
//   [32768  : 32832)  qbk_s [64]
//   [32832  : 65600)  pooled accumulator [64][512]
//   [65600  : 65664)  l accumulator [64]

// ---------------------------------------------------------------------------
// K0: qWk_s[k][d] = (sum_h q[k,h] * Wk[k,h,d]) / 16 ; qbk_s[k] = (q[k]·bk[k])/16
// grid 256 blocks (k = bid>>2, d-quarter = bid&3), 128 threads
__global__ __launch_bounds__(128)
void prep_kernel(const float* __restrict__ q, const float* __restrict__ Wk,
                 const float* __restrict__ bk,
                 float* __restrict__ qWk_s, float* __restrict__ qbk_s)
{
    const int k  = blockIdx.x >> 2;
    const int dq = blockIdx.x & 3;
    const int t  = threadIdx.x;            // 0..127
    const int d  = (dq << 7) + t;
    const float scale = 0.0625f;           // 1/sqrt(256)

    const float* qk  = q  + (k << 8);
    const float* wkk = Wk + ((size_t)k << 17);   // k*256*512

    float acc = 0.f;
    for (int h = 0; h < HDIM; ++h)
        acc = fmaf(qk[h], wkk[(h << 9) + d], acc);
    qWk_s[(k << 9) + d] = acc * scale;

    if (dq == 0) {
        float v = qk[t] * bk[(k << 8) + t] + qk[t + 128] * bk[(k << 8) + t + 128];
        for (int o = 32; o > 0; o >>= 1) v += __shfl_down(v, o);
        __shared__ float r2[2];
        if ((t & 63) == 0) r2[t >> 6] = v;
        __syncthreads();
        if (t == 0) qbk_s[k] = (r2[0] + r2[1]) * scale;
    }
}

// ---------------------------------------------------------------------------
// K1: fused scores -> exp -> (l, pooled_num) single pass over e.
// 512 threads (8 waves). Score mapping: k = t>>3, slice sl = t&7 (8 lanes/head,
// butterfly-reduced). Pooled mapping: thread owns column d = t, acc[64] in VGPRs.
// Partials merged across blocks with global fp32 atomics.
__global__ __launch_bounds__(512, 2)
void fused_attn(const float* __restrict__ e, const float* __restrict__ qWk_s,
                const float* __restrict__ qbk_s,
                float* __restrict__ pooled, float* __restrict__ lsum)
{
    __shared__ float e_lds[BATCH * DDIM];   // 32 KB
    __shared__ float p_lds[KHEADS][BATCH];  // 4 KB

    const int t  = threadIdx.x;
    const int k  = t >> 3;
    const int sl = t & 7;

    // Resident qWk slice: float4 chunks c = sl + 8i (bank-conflict-free reads of e)
    float4 qreg4[16];
    {
        const float4* qrow = (const float4*)(qWk_s + (k << 9));
        #pragma unroll
        for (int i = 0; i < 16; ++i) qreg4[i] = qrow[sl + (i << 3)];
    }
    const float qb = qbk_s[k];

    float acc[KHEADS];
    #pragma unroll
    for (int i = 0; i < KHEADS; ++i) acc[i] = 0.f;
    float l_acc = 0.f;

    for (int b = blockIdx.x; b < NBATCH; b += gridDim.x) {
        // ---- stage 16 rows of e into LDS (coalesced float4) ----
        const float4* src4 = (const float4*)(e + (size_t)b * (BATCH * DDIM));
        float4* dst4 = (float4*)e_lds;
        #pragma unroll
        for (int i = 0; i < 4; ++i) dst4[t + (i << 9)] = src4[t + (i << 9)];
        __syncthreads();

        // ---- score phase: s[k] per row, p = exp(s + qb) ----
        for (int r = 0; r < BATCH; ++r) {
            const float4* er4 = (const float4*)(e_lds + (r << 9));
            float s0 = 0.f, s1 = 0.f, s2 = 0.f, s3 = 0.f;
            #pragma unroll
            for (int i = 0; i < 16; ++i) {
                float4 ev4 = er4[sl + (i << 3)];
                float4 qv  = qreg4[i];
                s0 = fmaf(qv.x, ev4.x, s0);
                s1 = fmaf(qv.y, ev4.y, s1);
                s2 = fmaf(qv.z, ev4.z, s2);
                s3 = fmaf(qv.w, ev4.w, s3);
            }
            float s = (s0 + s1) + (s2 + s3);
            s += __shfl_xor(s, 1);
            s += __shfl_xor(s, 2);
            s += __shfl_xor(s, 4);
            float p = __expf(s + qb);    // scores ~N(0,0.45): no max-sub needed
            if (sl == 0) { p_lds[k][r] = p; l_acc += p; }
        }
        __syncthreads();

        // ---- pooled phase: acc[kk] += sum_r p[kk][r] * e[r][t] ----
        float ev[BATCH];
        #pragma unroll
        for (int r = 0; r < BATCH; ++r) ev[r] = e_lds[(r << 9) + t];
        #pragma unroll
        for (int kk = 0; kk < KHEADS; ++kk) {
            const float4* p4 = (const float4*)p_lds[kk];
            float4 a0 = p4[0], a1 = p4[1], a2 = p4[2], a3 = p4[3];
            float s = acc[kk];
            s = fmaf(a0.x, ev[0],  s); s = fmaf(a0.y, ev[1],  s);
            s = fmaf(a0.z, ev[2],  s); s = fmaf(a0.w, ev[3],  s);
            s = fmaf(a1.x, ev[4],  s); s = fmaf(a1.y, ev[5],  s);
            s = fmaf(a1.z, ev[6],  s); s = fmaf(a1.w, ev[7],  s);
            s = fmaf(a2.x, ev[8],  s); s = fmaf(a2.y, ev[9],  s);
            s = fmaf(a2.z, ev[10], s); s = fmaf(a2.w, ev[11], s);
            s = fmaf(a3.x, ev[12], s); s = fmaf(a3.y, ev[13], s);
            s = fmaf(a3.z, ev[14], s); s = fmaf(a3.w, ev[15], s);
            acc[kk] = s;
        }
        __syncthreads();   // protect e_lds/p_lds before next staging
    }

    // ---- merge block partials ----
    #pragma unroll
    for (int kk = 0; kk < KHEADS; ++kk)
        atomicAdd(&pooled[(kk << 9) + t], acc[kk]);
    if (sl == 0) atomicAdd(&lsum[k], l_acc);
}

// ---------------------------------------------------------------------------
// K2: h[k][t] = (pooled[k]/l[k]) · Wv[k][t] + bv[k][t];
//     mu[k] = h·mu_w + mu_b ; sigma[k] = exp(h·sigma_w + sigma_b)
// grid 64 (one per head), 256 threads (one per hidden unit)
__global__ __launch_bounds__(256)
void finalize_kernel(const float* __restrict__ pooled, const float* __restrict__ lsum,
                     const float* __restrict__ Wv, const float* __restrict__ bv,
                     const float* __restrict__ mu_w, const float* __restrict__ mu_b,
                     const float* __restrict__ sigma_w, const float* __restrict__ sigma_b,
                     float* __restrict__ out)
{
    const int k = blockIdx.x;
    const int t = threadIdx.x;   // 0..255
    __shared__ float pn[DDIM];
    __shared__ float redm[4], reds[4];

    const float inv_l = 1.0f / lsum[k];
    for (int d = t; d < DDIM; d += 256) pn[d] = pooled[(k << 9) + d] * inv_l;
    __syncthreads();

    const float* wv = Wv + (((size_t)k << 8) + t) * DDIM;
    float h = bv[(k << 8) + t];
    for (int d = 0; d < DDIM; d += 4) {
        float4 w4 = *(const float4*)&wv[d];
        h = fmaf(pn[d + 0], w4.x, h);
        h = fmaf(pn[d + 1], w4.y, h);
        h = fmaf(pn[d + 2], w4.z, h);
        h = fmaf(pn[d + 3], w4.w, h);
    }

    float pm = h * mu_w[t];
    float ps = h * sigma_w[t];
    for (int o = 32; o > 0; o >>= 1) {
        pm += __shfl_down(pm, o);
        ps += __shfl_down(ps, o);
    }
    if ((t & 63) == 0) { redm[t >> 6] = pm; reds[t >> 6] = ps; }
    __syncthreads();
    if (t == 0) {
        float m = (redm[0] + redm[1]) + (redm[2] + redm[3]);
        float s = (reds[0] + reds[1]) + (reds[2] + reds[3]);
        out[k]          = m + mu_b[0];
        out[KHEADS + k] = __expf(s + sigma_b[0]);
    }
}

// ---------------------------------------------------------------------------
extern "C" void kernel_launch(void* const* d_in, const int* in_sizes, int n_in,
                              void* d_out, int out_size, void* d_ws, size_t ws_size,
                              hipStream_t stream)
{
    const float* e       = (const float*)d_in[0];
    const float* q       = (const float*)d_in[1];
    const float* Wk      = (const float*)d_in[2];
    const float* bk      = (const float*)d_in[3];
    const float* Wv      = (const float*)d_in[4];
    const float* bv      = (const float*)d_in[5];
    const float* mu_w    = (const float*)d_in[6];
    const float* mu_b    = (const float*)d_in[7];
    const float* sigma_w = (const float*)d_in[8];
    const float* sigma_b = (const float*)d_in[9];
    float* out = (float*)d_out;

    float* ws     = (float*)d_ws;
    float* qWk_s  = ws;
    float* qbk_s  = ws + 32768;
    float* pooled = ws + 32832;
    float* lsum   = ws + 65600;

    // zero the accumulators (ws is poisoned 0xAA before every call)
    hipMemsetAsync(pooled, 0, (32768 + 64) * sizeof(float), stream);

    prep_kernel<<<256, 128, 0, stream>>>(q, Wk, bk, qWk_s, qbk_s);
    fused_attn<<<512, 512, 0, stream>>>(e, qWk_s, qbk_s, pooled, lsum);
    finalize_kernel<<<64, 256, 0, stream>>>(pooled, lsum, Wv, bv,
                                            mu_w, mu_b, sigma_w, sigma_b, out);
}

// Round 2
// 699.944 us; speedup vs baseline: 1.9040x; 1.9040x over previous
//
#include <hip/hip_runtime.h>
#include <math.h>
#include <stdint.h>

// Problem constants (fixed by the reference)
#define NROWS 200000
#define DDIM  512
#define HDIM  256
#define KHEADS 64
#define NB    32                 // rows per tile iteration
#define NITER (NROWS / NB)       // 6250 exactly
#define GRID  512                // 2 blocks/CU

typedef __attribute__((ext_vector_type(8))) short bf16x8;   // MFMA A/B frag (guide §3)
typedef __attribute__((ext_vector_type(4))) float f32x4;    // MFMA C/D frag

__device__ __forceinline__ uint32_t f2bf1(float x) {        // fp32 -> bf16 bits (RNE)
    uint32_t u = __float_as_uint(x);
    return (u + 0x7FFFu + ((u >> 16) & 1u)) >> 16;
}
__device__ __forceinline__ uint32_t pk2(float a, float b) {
    return f2bf1(a) | (f2bf1(b) << 16);
}

// ---------------------------------------------------------------------------
// prep: qwkb[k][d] = bf16( (sum_h q[k,h]*Wk[k,h,d]) / 16 )
// grid 512 = (k, d-octant), 256 thr = 64 d-lanes x 4 h-segments
__global__ __launch_bounds__(256)
void prep(const float* __restrict__ q, const float* __restrict__ Wk,
          unsigned short* __restrict__ qwkb)
{
    const int k    = blockIdx.x >> 3;
    const int dq   = blockIdx.x & 7;
    const int t    = threadIdx.x;
    const int cd   = t & 63;
    const int hseg = t >> 6;
    const int d    = dq * 64 + cd;
    const float* wk = Wk + ((size_t)k << 17);
    const float* qk = q + (k << 8);
    float s = 0.f;
    for (int h = hseg * 64; h < hseg * 64 + 64; ++h)
        s = fmaf(qk[h], wk[h * 512 + d], s);
    __shared__ float red[4][64];
    red[hseg][cd] = s;
    __syncthreads();
    if (t < 64) {
        float tot = (red[0][t] + red[1][t]) + (red[2][t] + red[3][t]);
        qwkb[(k << 9) + dq * 64 + t] = (unsigned short)f2bf1(tot * 0.0625f);
    }
}

// qbk[k] = (q[k]·bk[k]) / 16  — tiny
__global__ void qbk_kernel(const float* __restrict__ q, const float* __restrict__ bk,
                           float* __restrict__ qbk)
{
    int k = threadIdx.x;
    const float4* q4 = (const float4*)(q + (k << 8));
    const float4* b4 = (const float4*)(bk + (k << 8));
    float s = 0.f;
    for (int i = 0; i < 64; ++i) {
        float4 a = q4[i], b = b4[i];
        s += a.x * b.x + a.y * b.y + a.z * b.z + a.w * b.w;
    }
    qbk[k] = s * 0.0625f;
}

// ---------------------------------------------------------------------------
// fused_attn: per 32-row tile: stage e->bf16 LDS (two frag layouts),
// C1[row,head] = e·qWk^T via MFMA, p=exp(C1+qb), permute C->A layout,
// P[head,dcol] += p·e via MFMA (K=32). Accumulate P in 128 VGPRs.
__global__ __launch_bounds__(256, 2)
void fused_attn(const float* __restrict__ e,
                const unsigned short* __restrict__ qwkb,
                const float* __restrict__ qbk,
                float* __restrict__ pooled, float* __restrict__ lsum,
                float* __restrict__ parts, float* __restrict__ lparts,
                int use_parts)
{
    __shared__ char lds[65536];   // [0,32K): layoutA (GEMM1 A-frags), [32K,64K): layoutB (GEMM2 B-frags)

    const int t    = threadIdx.x;
    const int w    = t >> 6;      // wave 0..3 -> head tile
    const int lane = t & 63;
    const int c    = lane & 15;
    const int Q    = lane >> 4;

    // persistent qWk B-fragments: B[k=quad*8+j][n=head=w*16+c]
    bf16x8 bq[16];
    {
        const char* qb_ = (const char*)qwkb + (w * 16 + c) * 1024 + Q * 16;
        #pragma unroll
        for (int ks = 0; ks < 16; ++ks)
            bq[ks] = *(const bf16x8*)(qb_ + ks * 64);
    }
    const float qbias = qbk[w * 16 + c];

    f32x4 acc[32];
    #pragma unroll
    for (int i = 0; i < 32; ++i) { f32x4 z = {0.f, 0.f, 0.f, 0.f}; acc[i] = z; }
    float l_part = 0.f;

    for (int b = blockIdx.x; b < NITER; b += GRID) {
        __syncthreads();          // previous iteration's LDS reads complete
        // ---- stage 32x512 fp32 -> bf16 LDS, both layouts, 4x4 blocks/thread ----
        const float4* eg = (const float4*)(e + (size_t)b * (NB * DDIM));
        #pragma unroll
        for (int i = 0; i < 4; ++i) {
            const int bb = t + i * 256;
            const int rg = bb >> 7, dg = bb & 127;   // rowgroup(4 rows), dgroup(4 cols)
            float4 v0 = eg[(rg * 4 + 0) * 128 + dg];
            float4 v1 = eg[(rg * 4 + 1) * 128 + dg];
            float4 v2 = eg[(rg * 4 + 2) * 128 + dg];
            float4 v3 = eg[(rg * 4 + 3) * 128 + dg];
            const float* r0 = (const float*)&v0;
            const float* r1 = (const float*)&v1;
            const float* r2 = (const float*)&v2;
            const float* r3 = (const float*)&v3;
            // layoutA: element (row,d): chunk=(row>>4)*16+(d>>5), lane=(row&15)+((d>>3)&3)*16, byte=(d&7)*2
            {
                const int chA  = (rg >> 2) * 16 + (dg >> 3);
                const int lnD  = ((dg >> 1) & 3) * 16;
                const int byA  = (dg & 1) * 8;
                const int base = chA * 1024 + byA;
                const int sw   = chA & 7;
                int ln0 = (((rg & 3) * 4 + 0) + lnD) ^ sw;
                int ln1 = (((rg & 3) * 4 + 1) + lnD) ^ sw;
                int ln2 = (((rg & 3) * 4 + 2) + lnD) ^ sw;
                int ln3 = (((rg & 3) * 4 + 3) + lnD) ^ sw;
                *(uint2*)(lds + base + ln0 * 16) = make_uint2(pk2(r0[0], r0[1]), pk2(r0[2], r0[3]));
                *(uint2*)(lds + base + ln1 * 16) = make_uint2(pk2(r1[0], r1[1]), pk2(r1[2], r1[3]));
                *(uint2*)(lds + base + ln2 * 16) = make_uint2(pk2(r2[0], r2[1]), pk2(r2[2], r2[3]));
                *(uint2*)(lds + base + ln3 * 16) = make_uint2(pk2(r3[0], r3[1]), pk2(r3[2], r3[3]));
            }
            // layoutB: element (row,d): chunk=d>>4, lane=(d&15)+((row>>3)&3)*16, byte=(row&7)*2
            {
                const int chB  = dg >> 2;
                const int lnR  = ((rg >> 1) & 3) * 16;
                const int byB  = (rg & 1) * 8;
                const int base = 32768 + chB * 1024 + byB;
                const int sw   = chB & 7;
                #pragma unroll
                for (int i3 = 0; i3 < 4; ++i3) {
                    int ln = (((dg & 3) * 4 + i3) + lnR) ^ sw;
                    *(uint2*)(lds + base + ln * 16) =
                        make_uint2(pk2(r0[i3], r1[i3]), pk2(r2[i3], r3[i3]));
                }
            }
        }
        __syncthreads();

        // ---- GEMM1: C1'[row,head] for this wave's 16 heads, 2 row-tiles ----
        f32x4 c10 = {0.f, 0.f, 0.f, 0.f};
        f32x4 c11 = {0.f, 0.f, 0.f, 0.f};
        #pragma unroll
        for (int ks = 0; ks < 16; ++ks) {
            const bf16x8 a0 = *(const bf16x8*)(lds + ks * 1024        + ((lane ^ (ks & 7)) * 16));
            const bf16x8 a1 = *(const bf16x8*)(lds + (16 + ks) * 1024 + ((lane ^ ((16 + ks) & 7)) * 16));
            c10 = __builtin_amdgcn_mfma_f32_16x16x32_bf16(a0, bq[ks], c10, 0, 0, 0);
            c11 = __builtin_amdgcn_mfma_f32_16x16x32_bf16(a1, bq[ks], c11, 0, 0, 0);
        }

        // ---- exp (scores ~N(0,0.45): no max-subtraction needed) ----
        float pe0[4], pe1[4];
        #pragma unroll
        for (int r = 0; r < 4; ++r) {
            pe0[r] = __expf(c10[r] + qbias);
            pe1[r] = __expf(c11[r] + qbias);
            l_part += pe0[r] + pe1[r];
        }

        // ---- C-layout -> A-layout permute: A2[head=c][k=row=Q*8+j] ----
        float av[8];
        #pragma unroll
        for (int j = 0; j < 8; ++j) {
            int sq = (2 * Q + (j >> 2)) & 3;
            int sl = c + (sq << 4);
            float v0 = __shfl(pe0[j & 3], sl, 64);
            float v1 = __shfl(pe1[j & 3], sl, 64);
            av[j] = (Q >= 2) ? v1 : v0;
        }
        union { uint32_t u[4]; bf16x8 v; } a2;
        #pragma unroll
        for (int d2 = 0; d2 < 4; ++d2) a2.u[d2] = pk2(av[2 * d2], av[2 * d2 + 1]);

        // ---- GEMM2: P[head,dcol] += A2 · e  (one K=32 MFMA per 16-col tile) ----
        #pragma unroll
        for (int ntd = 0; ntd < 32; ++ntd) {
            const bf16x8 bf_ = *(const bf16x8*)(lds + 32768 + ntd * 1024 + ((lane ^ (ntd & 7)) * 16));
            acc[ntd] = __builtin_amdgcn_mfma_f32_16x16x32_bf16(a2.v, bf_, acc[ntd], 0, 0, 0);
        }
    }

    // ---- merge block partials ----
    float lt = l_part;
    lt += __shfl_xor(lt, 16, 64);
    lt += __shfl_xor(lt, 32, 64);

    if (use_parts) {
        float* pp = parts + (size_t)blockIdx.x * (KHEADS * DDIM);
        #pragma unroll
        for (int ntd = 0; ntd < 32; ++ntd)
            #pragma unroll
            for (int r = 0; r < 4; ++r)
                pp[(w * 16 + Q * 4 + r) * DDIM + ntd * 16 + c] = acc[ntd][r];
        if (Q == 0) lparts[blockIdx.x * KHEADS + w * 16 + c] = lt;
    } else {
        #pragma unroll
        for (int ntd = 0; ntd < 32; ++ntd)
            #pragma unroll
            for (int r = 0; r < 4; ++r)
                atomicAdd(&pooled[(w * 16 + Q * 4 + r) * DDIM + ntd * 16 + c], acc[ntd][r]);
        if (Q == 0) atomicAdd(&lsum[w * 16 + c], lt);
    }
}

// ---------------------------------------------------------------------------
// reduce_parts: pooled[o] = sum_b parts[b][o]; lsum likewise (block 256)
__global__ __launch_bounds__(128)
void reduce_parts(const float* __restrict__ parts, const float* __restrict__ lparts,
                  float* __restrict__ pooled, float* __restrict__ lsum)
{
    const int bid = blockIdx.x;
    if (bid < 256) {
        const int o = bid * 128 + threadIdx.x;
        float s = 0.f;
        #pragma unroll 4
        for (int b = 0; b < GRID; ++b) s += parts[(size_t)b * (KHEADS * DDIM) + o];
        pooled[o] = s;
    } else if (threadIdx.x < 64) {
        float s = 0.f;
        #pragma unroll 4
        for (int b = 0; b < GRID; ++b) s += lparts[b * KHEADS + threadIdx.x];
        lsum[threadIdx.x] = s;
    }
}

// ---------------------------------------------------------------------------
// finalize_partial: hval = (pooled[k]/l)·Wv[k,h] + bv[k,h];
// atomic partial dots with mu_w / sigma_w. grid 512 = (k, h-group of 32)
__global__ __launch_bounds__(256)
void finalize_partial(const float* __restrict__ pooled, const float* __restrict__ lsum,
                      const float* __restrict__ Wv, const float* __restrict__ bv,
                      const float* __restrict__ mu_w, const float* __restrict__ sigma_w,
                      float* __restrict__ macc, float* __restrict__ sacc)
{
    const int k  = blockIdx.x >> 3;
    const int hg = blockIdx.x & 7;
    const int t  = threadIdx.x;
    __shared__ float pn[DDIM];
    __shared__ float sm[32], ss[32];
    const float inv_l = 1.0f / lsum[k];
    pn[t]       = pooled[(k << 9) + t] * inv_l;
    pn[t + 256] = pooled[(k << 9) + t + 256] * inv_l;
    __syncthreads();
    const int hi = t >> 3, ds = t & 7;
    const int h  = hg * 32 + hi;
    const float4* wv4 = (const float4*)(Wv + ((size_t)(k * 256 + h) << 9));
    const float4* pn4 = (const float4*)pn;
    float s = 0.f;
    #pragma unroll
    for (int i = 0; i < 16; ++i) {
        float4 a  = pn4[ds + i * 8];
        float4 b_ = wv4[ds + i * 8];
        s += a.x * b_.x + a.y * b_.y + a.z * b_.z + a.w * b_.w;
    }
    s += __shfl_down(s, 4, 64);
    s += __shfl_down(s, 2, 64);
    s += __shfl_down(s, 1, 64);
    if (ds == 0) {
        float hval = s + bv[(k << 8) + h];
        sm[hi] = hval * mu_w[h];
        ss[hi] = hval * sigma_w[h];
    }
    __syncthreads();
    if (t == 0) {
        float m = 0.f, sg = 0.f;
        for (int i = 0; i < 32; ++i) { m += sm[i]; sg += ss[i]; }
        atomicAdd(&macc[k], m);
        atomicAdd(&sacc[k], sg);
    }
}

__global__ void final_out(const float* __restrict__ macc, const float* __restrict__ sacc,
                          const float* __restrict__ mu_b, const float* __restrict__ sigma_b,
                          float* __restrict__ out)
{
    int k = threadIdx.x;
    out[k]          = macc[k] + mu_b[0];
    out[KHEADS + k] = __expf(sacc[k] + sigma_b[0]);
}

// ---------------------------------------------------------------------------
extern "C" void kernel_launch(void* const* d_in, const int* in_sizes, int n_in,
                              void* d_out, int out_size, void* d_ws, size_t ws_size,
                              hipStream_t stream)
{
    const float* e       = (const float*)d_in[0];
    const float* q       = (const float*)d_in[1];
    const float* Wk      = (const float*)d_in[2];
    const float* bk      = (const float*)d_in[3];
    const float* Wv      = (const float*)d_in[4];
    const float* bv      = (const float*)d_in[5];
    const float* mu_w    = (const float*)d_in[6];
    const float* mu_b    = (const float*)d_in[7];
    const float* sigma_w = (const float*)d_in[8];
    const float* sigma_b = (const float*)d_in[9];
    float* out = (float*)d_out;

    char* wsb = (char*)d_ws;
    unsigned short* qwkb = (unsigned short*)wsb;        // 65536 B
    float* qbk    = (float*)(wsb + 65536);              // 256 B
    float* pooled = (float*)(wsb + 65792);              // 131072 B
    float* lsum   = (float*)(wsb + 196864);             // 256 B
    float* macc   = (float*)(wsb + 197120);             // 256 B
    float* sacc   = (float*)(wsb + 197376);             // 256 B
    float* parts  = (float*)(wsb + 197632);             // GRID*128KB
    float* lparts = (float*)(wsb + 197632 + (size_t)GRID * KHEADS * DDIM * 4);
    const size_t need = 197632 + (size_t)GRID * KHEADS * DDIM * 4 + (size_t)GRID * KHEADS * 4;
    const int use_parts = (ws_size >= need) ? 1 : 0;

    if (use_parts)
        hipMemsetAsync(macc, 0, 512, stream);                 // macc+sacc
    else
        hipMemsetAsync(pooled, 0, 131072 + 768, stream);      // pooled+lsum+macc+sacc

    prep<<<512, 256, 0, stream>>>(q, Wk, qwkb);
    qbk_kernel<<<1, 64, 0, stream>>>(q, bk, qbk);
    fused_attn<<<GRID, 256, 0, stream>>>(e, qwkb, qbk, pooled, lsum, parts, lparts, use_parts);
    if (use_parts)
        reduce_parts<<<257, 128, 0, stream>>>(parts, lparts, pooled, lsum);
    finalize_partial<<<512, 256, 0, stream>>>(pooled, lsum, Wv, bv, mu_w, sigma_w, macc, sacc);
    final_out<<<1, 64, 0, stream>>>(macc, sacc, mu_b, sigma_b, out);
}